// Round 2
// baseline (621.104 us; speedup 1.0000x reference)
//
#include <hip/hip_runtime.h>

// Problem constants (from reference)
#define B_  16
#define T_  2048
#define IN_ 512
#define H_  512
#define M_  (B_ * T_)          // 32768 rows of the GEMM

static __device__ __forceinline__ float4 ld4(const float* p) {
    return *reinterpret_cast<const float4*>(p);
}

// ---------------------------------------------------------------------------
// Kernel 1: h[m][n] = sum_k x[m][k] * W[n][k] + b[n]   (fp32, vector ALU)
// Tile: BM=128 x BN=64, BK=16. 256 threads, 8x4 micro-tile per thread.
// ---------------------------------------------------------------------------
#define BM 128
#define BN 64
#define BK 16
#define LDA (BM + 4)   // 132 floats per As row: keeps 16B alignment, breaks conflicts
#define LDB (BN + 4)   // 68 floats per Bs row

__global__ __launch_bounds__(256)
void gemm_xwT(const float* __restrict__ X, const float* __restrict__ W,
              const float* __restrict__ bias, float* __restrict__ Hout) {
    __shared__ float As[BK][LDA];
    __shared__ float Bs[BK][LDB];

    const int tid = threadIdx.x;
    const int m0  = blockIdx.x * BM;   // 256 tiles
    const int n0  = blockIdx.y * BN;   // 8 tiles

    const int tn = tid & 15;           // 16 col groups of 4
    const int tm = tid >> 4;           // 16 row groups (4 + 4 split by 64)

    // staging indices: each thread loads 2 float4 of A, 1 float4 of B per K-tile
    const int arow = tid >> 2;         // 0..63
    const int kph  = (tid & 3) * 4;    // 0,4,8,12

    float acc[8][4];
#pragma unroll
    for (int i = 0; i < 8; ++i)
#pragma unroll
        for (int j = 0; j < 4; ++j) acc[i][j] = 0.0f;

    for (int k0 = 0; k0 < IN_; k0 += BK) {
        // ---- stage A (128x16) ----
        float4 a0 = ld4(&X[(size_t)(m0 + arow)      * IN_ + k0 + kph]);
        float4 a1 = ld4(&X[(size_t)(m0 + arow + 64) * IN_ + k0 + kph]);
        // ---- stage B (64x16): B-row == arow, one float4 each ----
        float4 bv = ld4(&W[(size_t)(n0 + arow) * IN_ + k0 + kph]);

        As[kph + 0][arow] = a0.x;  As[kph + 1][arow] = a0.y;
        As[kph + 2][arow] = a0.z;  As[kph + 3][arow] = a0.w;
        As[kph + 0][arow + 64] = a1.x;  As[kph + 1][arow + 64] = a1.y;
        As[kph + 2][arow + 64] = a1.z;  As[kph + 3][arow + 64] = a1.w;
        Bs[kph + 0][arow] = bv.x;  Bs[kph + 1][arow] = bv.y;
        Bs[kph + 2][arow] = bv.z;  Bs[kph + 3][arow] = bv.w;
        __syncthreads();

#pragma unroll
        for (int k = 0; k < BK; ++k) {
            float4 av0 = ld4(&As[k][tm * 4]);
            float4 av1 = ld4(&As[k][tm * 4 + 64]);
            float4 bw  = ld4(&Bs[k][tn * 4]);
            const float am[8] = {av0.x, av0.y, av0.z, av0.w,
                                 av1.x, av1.y, av1.z, av1.w};
            const float bn4[4] = {bw.x, bw.y, bw.z, bw.w};
#pragma unroll
            for (int i = 0; i < 8; ++i)
#pragma unroll
                for (int j = 0; j < 4; ++j)
                    acc[i][j] = fmaf(am[i], bn4[j], acc[i][j]);
        }
        __syncthreads();
    }

    // epilogue: + bias, store float4 per row
    float4 bb = ld4(&bias[n0 + tn * 4]);
#pragma unroll
    for (int i = 0; i < 8; ++i) {
        int row = m0 + tm * 4 + (i < 4 ? i : 64 + (i - 4));
        float4 o;
        o.x = acc[i][0] + bb.x;  o.y = acc[i][1] + bb.y;
        o.z = acc[i][2] + bb.z;  o.w = acc[i][3] + bb.w;
        *reinterpret_cast<float4*>(&Hout[(size_t)row * H_ + n0 + tn * 4]) = o;
    }
}

// ---------------------------------------------------------------------------
// Kernel 2: GIF neuron scan. One thread per (b, h) chain; T=2048 steps.
// ---------------------------------------------------------------------------
__global__ __launch_bounds__(256)
void gif_scan(const float* __restrict__ Hbuf, float* __restrict__ spikes,
              float* __restrict__ vout, float* __restrict__ thout) {
    const int gid = blockIdx.x * 256 + threadIdx.x;   // 0..8191
    const int b = gid >> 9;
    const int h = gid & 511;

    const float* ip = Hbuf   + (size_t)b * T_ * H_ + h;
    float*       sp = spikes + (size_t)b * T_ * H_ + h;

    const float DECAY_F = 0.9048374180359595f;  // exp(-1/10)
    const float ALPHA_F = 0.01f;

    float v = 0.0f, theta = 1.0f;
    float nxt = ip[0];
    for (int t = 0; t < T_; ++t) {
        float cur = nxt;
        int tnext = (t + 1 < T_) ? (t + 1) : t;
        nxt = ip[(size_t)tnext * H_];              // prefetch, independent of chain

        v = v * DECAY_F + cur;
        float cl = 32.0f * theta;                  // L * theta * 2
        v = fminf(fmaxf(v, -cl), cl);
        float s = floorf(v / theta);               // IEEE div (no fast-math)
        s = fminf(fmaxf(s, 0.0f), 16.0f);
        v = v - s * theta;
        theta = theta + ALPHA_F * s - ALPHA_F * (theta - 1.0f);

        sp[(size_t)t * H_] = s;
    }
    vout[gid]  = v;
    thout[gid] = theta;
}

// ---------------------------------------------------------------------------
extern "C" void kernel_launch(void* const* d_in, const int* in_sizes, int n_in,
                              void* d_out, int out_size, void* d_ws, size_t ws_size,
                              hipStream_t stream) {
    const float* x    = (const float*)d_in[0];   // [16, 2048, 512]
    const float* W    = (const float*)d_in[1];   // [512, 512]
    const float* bias = (const float*)d_in[2];   // [512]

    float* out   = (float*)d_out;                // spikes | v_f | theta_f
    float* hbuf  = (float*)d_ws;                 // 64 MB scratch for h

    float* spikes = out;
    float* v_f    = out + (size_t)B_ * T_ * H_;
    float* th_f   = v_f + (size_t)B_ * H_;

    dim3 grid(M_ / BM, H_ / BN);                 // 256 x 8
    gemm_xwT<<<grid, 256, 0, stream>>>(x, W, bias, hbuf);
    gif_scan<<<(B_ * H_) / 256, 256, 0, stream>>>(hbuf, spikes, v_f, th_f);
}

// Round 3
// 442.431 us; speedup vs baseline: 1.4038x; 1.4038x over previous
//
#include <hip/hip_runtime.h>

// Problem constants (from reference)
#define B_  16
#define T_  2048
#define IN_ 512
#define H_  512
#define M_  (B_ * T_)          // 32768 rows of the GEMM

static __device__ __forceinline__ float4 ld4(const float* p) {
    return *reinterpret_cast<const float4*>(p);
}

// ---------------------------------------------------------------------------
// Kernel 1: h[m][n] = sum_k x[m][k] * W[n][k] + b[n]   (fp32, vector ALU)
// Tile: BM=128 x BN=128, BK=16. 256 threads, 8x8 micro-tile per thread.
// FMA:LDS cycle ratio per k-step (per wave): 128 VALU cyc vs ~62 LDS cyc ->
// LDS pipe hidden under VALU. Staging: 4 float4 global loads/thread/k-tile.
// ---------------------------------------------------------------------------
#define BM 128
#define BN 128
#define BK 16
#define LDT (BM + 4)   // 132: pad breaks power-of-2 strides; 2-way aliasing is free

__global__ __launch_bounds__(256)
void gemm_xwT(const float* __restrict__ X, const float* __restrict__ W,
              const float* __restrict__ bias, float* __restrict__ Hout) {
    __shared__ float As[BK][LDT];
    __shared__ float Bs[BK][LDT];

    const int tid = threadIdx.x;
    const int m0  = blockIdx.x * BM;   // 256 tiles
    const int n0  = blockIdx.y * BN;   // 4 tiles

    const int tx = tid & 15;           // B-col group (8 cols)
    const int ty = tid >> 4;           // A-row group (8 rows)

    // staging: each thread loads 2 A-rows and 2 B-rows, one float4 each
    const int row = tid >> 2;          // 0..63
    const int kph = (tid & 3) * 4;     // 0,4,8,12

    float acc[8][8];
#pragma unroll
    for (int i = 0; i < 8; ++i)
#pragma unroll
        for (int j = 0; j < 8; ++j) acc[i][j] = 0.0f;

    for (int k0 = 0; k0 < IN_; k0 += BK) {
        float4 a0 = ld4(&X[(size_t)(m0 + row)      * IN_ + k0 + kph]);
        float4 a1 = ld4(&X[(size_t)(m0 + row + 64) * IN_ + k0 + kph]);
        float4 b0 = ld4(&W[(size_t)(n0 + row)      * IN_ + k0 + kph]);
        float4 b1 = ld4(&W[(size_t)(n0 + row + 64) * IN_ + k0 + kph]);

        As[kph + 0][row]      = a0.x;  As[kph + 1][row]      = a0.y;
        As[kph + 2][row]      = a0.z;  As[kph + 3][row]      = a0.w;
        As[kph + 0][row + 64] = a1.x;  As[kph + 1][row + 64] = a1.y;
        As[kph + 2][row + 64] = a1.z;  As[kph + 3][row + 64] = a1.w;
        Bs[kph + 0][row]      = b0.x;  Bs[kph + 1][row]      = b0.y;
        Bs[kph + 2][row]      = b0.z;  Bs[kph + 3][row]      = b0.w;
        Bs[kph + 0][row + 64] = b1.x;  Bs[kph + 1][row + 64] = b1.y;
        Bs[kph + 2][row + 64] = b1.z;  Bs[kph + 3][row + 64] = b1.w;
        __syncthreads();

#pragma unroll
        for (int k = 0; k < BK; ++k) {
            float4 av0 = ld4(&As[k][ty * 8]);
            float4 av1 = ld4(&As[k][ty * 8 + 4]);
            float4 bv0 = ld4(&Bs[k][tx * 8]);
            float4 bv1 = ld4(&Bs[k][tx * 8 + 4]);
            const float am[8] = {av0.x, av0.y, av0.z, av0.w,
                                 av1.x, av1.y, av1.z, av1.w};
            const float bn8[8] = {bv0.x, bv0.y, bv0.z, bv0.w,
                                  bv1.x, bv1.y, bv1.z, bv1.w};
#pragma unroll
            for (int i = 0; i < 8; ++i)
#pragma unroll
                for (int j = 0; j < 8; ++j)
                    acc[i][j] = fmaf(am[i], bn8[j], acc[i][j]);
        }
        __syncthreads();
    }

    // epilogue: + bias, two float4 stores per row
    float4 bb0 = ld4(&bias[n0 + tx * 8]);
    float4 bb1 = ld4(&bias[n0 + tx * 8 + 4]);
#pragma unroll
    for (int i = 0; i < 8; ++i) {
        const int rowo = m0 + ty * 8 + i;
        float4 o0, o1;
        o0.x = acc[i][0] + bb0.x;  o0.y = acc[i][1] + bb0.y;
        o0.z = acc[i][2] + bb0.z;  o0.w = acc[i][3] + bb0.w;
        o1.x = acc[i][4] + bb1.x;  o1.y = acc[i][5] + bb1.y;
        o1.z = acc[i][6] + bb1.z;  o1.w = acc[i][7] + bb1.w;
        *reinterpret_cast<float4*>(&Hout[(size_t)rowo * H_ + n0 + tx * 8])     = o0;
        *reinterpret_cast<float4*>(&Hout[(size_t)rowo * H_ + n0 + tx * 8 + 4]) = o1;
    }
}

// ---------------------------------------------------------------------------
// Kernel 2: GIF neuron scan. One thread per (b, h) chain; T=2048 steps.
// Depth-16 register prefetch: 16 independent loads in flight while computing
// the current 16 steps -> slack ~1100 cyc > ~900 cyc HBM latency.
// Arithmetic kept expression-identical to the passing Round-2 version.
// ---------------------------------------------------------------------------
#define PF 16

__global__ __launch_bounds__(64)
void gif_scan(const float* __restrict__ Hbuf, float* __restrict__ spikes,
              float* __restrict__ vout, float* __restrict__ thout) {
    const int gid = blockIdx.x * 64 + threadIdx.x;    // 0..8191
    const int b = gid >> 9;
    const int h = gid & 511;

    const float* ip = Hbuf   + (size_t)b * T_ * H_ + h;
    float*       sp = spikes + (size_t)b * T_ * H_ + h;

    const float DECAY_F = 0.9048374180359595f;  // exp(-1/10)
    const float ALPHA_F = 0.01f;

    float buf[PF];
#pragma unroll
    for (int j = 0; j < PF; ++j) buf[j] = ip[(size_t)j * H_];

    float v = 0.0f, theta = 1.0f;
    for (int t0 = 0; t0 < T_; t0 += PF) {
        float nbuf[PF];
        const int tnx = t0 + PF;
        if (tnx < T_) {
#pragma unroll
            for (int j = 0; j < PF; ++j) nbuf[j] = ip[(size_t)(tnx + j) * H_];
        }
#pragma unroll
        for (int j = 0; j < PF; ++j) {
            float cur = buf[j];
            v = v * DECAY_F + cur;
            float cl = 32.0f * theta;                  // L * theta * 2
            v = fminf(fmaxf(v, -cl), cl);
            float s = floorf(v / theta);               // IEEE div (no fast-math)
            s = fminf(fmaxf(s, 0.0f), 16.0f);
            v = v - s * theta;
            theta = theta + ALPHA_F * s - ALPHA_F * (theta - 1.0f);
            sp[(size_t)(t0 + j) * H_] = s;
        }
#pragma unroll
        for (int j = 0; j < PF; ++j) buf[j] = nbuf[j];
    }
    vout[gid]  = v;
    thout[gid] = theta;
}

// ---------------------------------------------------------------------------
extern "C" void kernel_launch(void* const* d_in, const int* in_sizes, int n_in,
                              void* d_out, int out_size, void* d_ws, size_t ws_size,
                              hipStream_t stream) {
    const float* x    = (const float*)d_in[0];   // [16, 2048, 512]
    const float* W    = (const float*)d_in[1];   // [512, 512]
    const float* bias = (const float*)d_in[2];   // [512]

    float* out   = (float*)d_out;                // spikes | v_f | theta_f
    float* hbuf  = (float*)d_ws;                 // 64 MB scratch for h

    float* spikes = out;
    float* v_f    = out + (size_t)B_ * T_ * H_;
    float* th_f   = v_f + (size_t)B_ * H_;

    dim3 grid(M_ / BM, H_ / BN);                 // 256 x 4
    gemm_xwT<<<grid, 256, 0, stream>>>(x, W, bias, hbuf);
    gif_scan<<<(B_ * H_) / 64, 64, 0, stream>>>(hbuf, spikes, v_f, th_f);
}